// Round 18
// baseline (32.142 us; speedup 1.0000x reference)
//
#include <hip/hip_runtime.h>
#include <hip/hip_fp16.h>

typedef _Float16 half8 __attribute__((ext_vector_type(8)));
typedef float f32x4 __attribute__((ext_vector_type(4)));

#define CIN   128
#define COUT  128
#define HH    32
#define WW    32
#define LTOT  1024
#define KKT   9
#define KDIM  1152

// LDS: B tile 6 rows x 32 cols x 256B = 48KB; reduction buffer (34.8KB) reuses it.
// 48KB/block -> 2 co-resident blocks/CU (96KB of 160KB).
#define SMEM_BYTES 49152

// ---- prep: fragment-ordered weights ----
// wt3[q*1024 + o*8 + j] = f16(w[(o*128 + c)*9 + kk]),  q = kk*16 + (c>>3), j = c&7.
__global__ void prep_w_kernel(const float* __restrict__ w, _Float16* __restrict__ wt) {
  int i = blockIdx.x * 256 + threadIdx.x;   // 576 blocks cover 147456
  int q = i >> 10;
  int o = (i >> 3) & 127;
  int j = i & 7;
  int kk = q >> 4;
  int c  = ((q & 15) << 3) + j;
  wt[i] = (_Float16)w[(o * CIN + c) * KKT + kk];
}

// 512 blocks x 256 threads (4 waves). Block tile 64(o) x 128(l), o-split so
// per-CU A traffic is unchanged vs r12 while TWO independent blocks co-reside
// per CU at the same total occupancy (8 waves/CU = 2/SIMD, 128-VGPR regime):
// one block's B-build/epilogue overlaps the other's K-loop. 4 waves = kh
// (K-half) x 2n, wave tile 64o x 64l, mfma 16x16x32 f16, barrier-free K-loop,
// A direct global->VGPR, B resident LDS, mask folded into B-frags (pk_mul).
__global__ __launch_bounds__(256, 4)
void conv_mfma_kernel(const float* __restrict__ x,
                      const _Float16* __restrict__ wt,
                      const float* __restrict__ mask,
                      const float* __restrict__ bias,
                      float* __restrict__ out) {
  extern __shared__ char smem[];
  const int tid = threadIdx.x;
  int bid = blockIdx.x;
  bid = (bid & 7) * 64 + (bid >> 3);     // XCD swizzle, bijective (512 % 8 == 0)
  const int b  = bid >> 4;
  const int o0 = (bid & 1) << 6;         // 64 o per block
  const int lq = (bid >> 1) & 7;
  const int l0 = lq << 7;                // 128 l per block
  const int h0 = lq << 2;                // 4 output h-rows per block

  const int lane = tid & 63, wid = tid >> 6;
  const int lr = lane & 15, lg = lane >> 4;
  const int kh = wid >> 1;               // K-half: 0 -> c 0..63, 1 -> c 64..127
  const int wq = wid & 1;
  const int nw = wq << 6;                // wave n base {0,64}

  // ---- mask preload: 36 f32 per lane (kk x nj), as in r12 ----
  float mv[9][4];
  {
    const float* mr = mask + l0 + nw + lr;
#pragma unroll
    for (int kk = 0; kk < 9; ++kk)
#pragma unroll
      for (int nj = 0; nj < 4; ++nj)
        mv[kk][nj] = mr[kk * LTOT + nj * 16];
  }

  // ---- B-build: x[b][c][hg][w] -> fp16 tile, two passes (256 threads) ----
  const int wv = tid & 31, cg = tid >> 5;          // col (w), chunk-group 0..7
  const float* xb = x + (size_t)b * CIN * LTOT;
  for (int p = 0; p < 2; ++p) {
    const int q = cg + p * 8;                      // 16-B chunk 0..15 (8 c's)
    char* bdst = smem + wv * 256 + ((q ^ (wv & 15)) << 4);
    float fr[6][8];
#pragma unroll
    for (int r = 0; r < 6; ++r) {
      const int hg = h0 - 1 + r;
      if ((unsigned)hg < (unsigned)HH) {           // block-uniform branch
        const float* s = xb + (size_t)q * 8 * LTOT + hg * WW + wv;
#pragma unroll
        for (int j = 0; j < 8; ++j) fr[r][j] = s[(size_t)j * LTOT];
      }
    }
    asm volatile("s_waitcnt vmcnt(0)" ::: "memory");
#pragma unroll
    for (int r = 0; r < 6; ++r) {
      const int hg = h0 - 1 + r;
      half8 v = (half8){0, 0, 0, 0, 0, 0, 0, 0};
      if ((unsigned)hg < (unsigned)HH) {
#pragma unroll
        for (int j = 0; j < 8; ++j) v[j] = (_Float16)fr[r][j];
      }
      *(half8*)(bdst + r * 8192) = v;
    }
  }
#pragma unroll
  for (int kk = 0; kk < 9; ++kk)
#pragma unroll
    for (int nj = 0; nj < 4; ++nj)
      asm volatile("" : "+v"(mv[kk][nj]));         // keep masks resident past drains
  __syncthreads();                                 // B tile visible to all waves

  // per-lane A base: byte addr(q, o) = q*2048 + o*16; q = qb + lg, o = o0+mi*16+lr
  const char* abase = (const char*)wt + lg * 2048 + (o0 + lr) * 16;

  f32x4 acc[4][4];                                 // [mi][nj], 64 VGPR
#pragma unroll
  for (int mi = 0; mi < 4; ++mi)
#pragma unroll
    for (int nj = 0; nj < 4; ++nj)
      acc[mi][nj] = (f32x4){0.f, 0.f, 0.f, 0.f};

  // ---- barrier-free 9-tap loop (r12 schedule) ----
#pragma unroll
  for (int kk = 0; kk < 9; ++kk) {
    const int di = (kk * 11) >> 5;               // kk/3
    const int dj = kk - 3 * di;

    const char* Bp[4];
    int xk[4];
    _Float16 mh[4];
#pragma unroll
    for (int nj = 0; nj < 4; ++nj) {
      const int wb = ((nj & 1) << 4) + lr + dj - 1;
      const bool vld = (unsigned)wb < (unsigned)WW;
      const int wc = vld ? wb : 0;
      const int hrow = (nw >> 5) + (nj >> 1) + di;   // 0..5
      Bp[nj] = smem + hrow * 8192 + wc * 256;
      xk[nj] = wc & 15;
      mh[nj] = (_Float16)(vld ? mv[kk][nj] : 0.f);
    }

    __builtin_amdgcn_s_setprio(1);
#pragma unroll
    for (int s = 0; s < 2; ++s) {
      const int qb = kk * 16 + (kh * 2 + s) * 4;
      const char* ab = abase + qb * 2048;
      const int q = qb + lg;
      half8 a0 = *(const half8*)(ab);
      half8 a1 = *(const half8*)(ab + 256);
      half8 a2 = *(const half8*)(ab + 512);
      half8 a3 = *(const half8*)(ab + 768);
      half8 b0 = *(const half8*)(Bp[0] + (((q & 15) ^ xk[0]) << 4)) * mh[0];
      half8 b1 = *(const half8*)(Bp[1] + (((q & 15) ^ xk[1]) << 4)) * mh[1];
      half8 b2 = *(const half8*)(Bp[2] + (((q & 15) ^ xk[2]) << 4)) * mh[2];
      half8 b3 = *(const half8*)(Bp[3] + (((q & 15) ^ xk[3]) << 4)) * mh[3];
      acc[0][0] = __builtin_amdgcn_mfma_f32_16x16x32_f16(a0, b0, acc[0][0], 0, 0, 0);
      acc[1][0] = __builtin_amdgcn_mfma_f32_16x16x32_f16(a1, b0, acc[1][0], 0, 0, 0);
      acc[2][0] = __builtin_amdgcn_mfma_f32_16x16x32_f16(a2, b0, acc[2][0], 0, 0, 0);
      acc[3][0] = __builtin_amdgcn_mfma_f32_16x16x32_f16(a3, b0, acc[3][0], 0, 0, 0);
      acc[0][1] = __builtin_amdgcn_mfma_f32_16x16x32_f16(a0, b1, acc[0][1], 0, 0, 0);
      acc[1][1] = __builtin_amdgcn_mfma_f32_16x16x32_f16(a1, b1, acc[1][1], 0, 0, 0);
      acc[2][1] = __builtin_amdgcn_mfma_f32_16x16x32_f16(a2, b1, acc[2][1], 0, 0, 0);
      acc[3][1] = __builtin_amdgcn_mfma_f32_16x16x32_f16(a3, b1, acc[3][1], 0, 0, 0);
      acc[0][2] = __builtin_amdgcn_mfma_f32_16x16x32_f16(a0, b2, acc[0][2], 0, 0, 0);
      acc[1][2] = __builtin_amdgcn_mfma_f32_16x16x32_f16(a1, b2, acc[1][2], 0, 0, 0);
      acc[2][2] = __builtin_amdgcn_mfma_f32_16x16x32_f16(a2, b2, acc[2][2], 0, 0, 0);
      acc[3][2] = __builtin_amdgcn_mfma_f32_16x16x32_f16(a3, b2, acc[3][2], 0, 0, 0);
      acc[0][3] = __builtin_amdgcn_mfma_f32_16x16x32_f16(a0, b3, acc[0][3], 0, 0, 0);
      acc[1][3] = __builtin_amdgcn_mfma_f32_16x16x32_f16(a1, b3, acc[1][3], 0, 0, 0);
      acc[2][3] = __builtin_amdgcn_mfma_f32_16x16x32_f16(a2, b3, acc[2][3], 0, 0, 0);
      acc[3][3] = __builtin_amdgcn_mfma_f32_16x16x32_f16(a3, b3, acc[3][3], 0, 0, 0);
    }
    __builtin_amdgcn_s_setprio(0);
  }

  // ---- K-split reduction through LDS (B region dead after this barrier) ----
  __syncthreads();
  char* red = smem + wq * 17408 + lane * 272;
  if (kh == 1) {
#pragma unroll
    for (int mi = 0; mi < 4; ++mi)
#pragma unroll
      for (int nj = 0; nj < 4; ++nj)
        *(f32x4*)(red + (mi * 4 + nj) * 16) = acc[mi][nj];
  }
  __syncthreads();

  if (kh == 0) {
#pragma unroll
    for (int mi = 0; mi < 4; ++mi)
#pragma unroll
      for (int nj = 0; nj < 4; ++nj) {
        f32x4 p = *(const f32x4*)(red + (mi * 4 + nj) * 16);
        acc[mi][nj].x += p.x; acc[mi][nj].y += p.y;
        acc[mi][nj].z += p.z; acc[mi][nj].w += p.w;
      }

    // ---- epilogue: C/D layout col(l)=lane&15, row(o)=(lane>>4)*4+rr ----
    float* outb = out + (size_t)b * COUT * LTOT + (size_t)o0 * LTOT + l0;
#pragma unroll
    for (int mi = 0; mi < 4; ++mi) {
#pragma unroll
      for (int rr = 0; rr < 4; ++rr) {
        const int o = mi * 16 + lg * 4 + rr;
        const float bv = bias[o0 + o];
        float* orow = outb + (size_t)o * LTOT + nw + lr;
#pragma unroll
        for (int nj = 0; nj < 4; ++nj)
          orow[nj * 16] = acc[mi][nj][rr] + bv;
      }
    }
  }
}

extern "C" void kernel_launch(void* const* d_in, const int* in_sizes, int n_in,
                              void* d_out, int out_size, void* d_ws, size_t ws_size,
                              hipStream_t stream) {
  const float* x    = (const float*)d_in[0];
  const float* mask = (const float*)d_in[1];
  const float* w    = (const float*)d_in[2];
  const float* bias = (const float*)d_in[3];
  float* out = (float*)d_out;
  _Float16* wt = (_Float16*)d_ws;

  (void)hipFuncSetAttribute(reinterpret_cast<const void*>(conv_mfma_kernel),
                            hipFuncAttributeMaxDynamicSharedMemorySize, SMEM_BYTES);

  prep_w_kernel<<<576, 256, 0, stream>>>(w, wt);
  conv_mfma_kernel<<<512, 256, SMEM_BYTES, stream>>>(x, wt, mask, bias, out);
}

// Round 19
// 27.142 us; speedup vs baseline: 1.1842x; 1.1842x over previous
//
#include <hip/hip_runtime.h>
#include <hip/hip_fp16.h>

typedef _Float16 half8 __attribute__((ext_vector_type(8)));
typedef float f32x4 __attribute__((ext_vector_type(4)));

#define CIN   128
#define COUT  128
#define HH    32
#define WW    32
#define LTOT  1024
#define KKT   9
#define KDIM  1152

// LDS: B tile 6 rows x 32 cols x 256B = 48KB at [0, 49152).
// After the loop, [0,69632) reused as the K-split reduction buffer.
#define SMEM_BYTES 69632

// ---- prep: fragment-ordered weights ----
// wt3[q*1024 + o*8 + j] = f16(w[(o*128 + c)*9 + kk]),  q = kk*16 + (c>>3), j = c&7.
__global__ void prep_w_kernel(const float* __restrict__ w, _Float16* __restrict__ wt) {
  int i = blockIdx.x * 256 + threadIdx.x;   // 576 blocks cover 147456
  int q = i >> 10;
  int o = (i >> 3) & 127;
  int j = i & 7;
  int kk = q >> 4;
  int c  = ((q & 15) << 3) + j;
  wt[i] = (_Float16)w[(o * CIN + c) * KKT + kk];
}

// BEST CONFIG (r12, 24.98 us): 256 blocks x 512 threads (8 waves, 2/SIMD).
// Block tile 128o x 128l, one image-b. K-SPLIT: waves 0-3 (kh=0) / 4-7 (kh=1)
// each do half of c per tap over the same 2x2 grid of 64x64 wave tiles; LDS
// reduction at the end. A-fragments: DIRECT global->VGPR from wt3 (L2-resident,
// no LDS staging, no barriers, no vmcnt choreography — compiler schedules).
// B: fp16 tile resident in LDS, built once in-kernel from f32 x (fused
// transpose+convert); mask folded into B-fragments via v_pk_mul_f16 (no
// separate fold pass). XOR-16 chunk swizzle on both write and read sides.
__global__ __launch_bounds__(512, 2)
void conv_mfma_kernel(const float* __restrict__ x,
                      const _Float16* __restrict__ wt,
                      const float* __restrict__ mask,
                      const float* __restrict__ bias,
                      float* __restrict__ out) {
  extern __shared__ char smem[];
  const int tid = threadIdx.x;
  int bid = blockIdx.x;
  bid = (bid & 7) * 32 + (bid >> 3);     // XCD swizzle, bijective (256 % 8 == 0)
  const int b  = bid >> 3;
  const int l0 = (bid & 7) << 7;         // 128 l per block
  const int h0 = (bid & 7) << 2;         // 4 h-rows per block

  const int lane = tid & 63, wid = tid >> 6;
  const int lr = lane & 15, lg = lane >> 4;
  const int kh = wid >> 2;               // K-half: 0 -> c 0..63, 1 -> c 64..127
  const int wq = wid & 3;
  const int mw = (wq >> 1) << 6;         // wave m base {0,64}
  const int nw = (wq & 1) << 6;          // wave n base {0,64}

  // ---- mask preload: 36 scalars per lane (kk x nj) ----
  float mv[9][4];
  {
    const float* mr = mask + l0 + nw + lr;
#pragma unroll
    for (int kk = 0; kk < 9; ++kk)
#pragma unroll
      for (int nj = 0; nj < 4; ++nj)
        mv[kk][nj] = mr[kk * LTOT + nj * 16];
  }

  // ---- B-build: x[b][c][hg][w] -> fp16 tile, single pass (512 threads) ----
  const int wv = tid & 31, q16 = tid >> 5;         // col (w), 16-B chunk 0..15
  char* bdst = smem + wv * 256 + ((q16 ^ (wv & 15)) << 4);
  const float* xb = x + (size_t)b * CIN * LTOT;
  {
    float fr[6][8];
#pragma unroll
    for (int r = 0; r < 6; ++r) {
      const int hg = h0 - 1 + r;
      if ((unsigned)hg < (unsigned)HH) {           // block-uniform branch
        const float* s = xb + (size_t)q16 * 8 * LTOT + hg * WW + wv;
#pragma unroll
        for (int j = 0; j < 8; ++j) fr[r][j] = s[(size_t)j * LTOT];
      }
    }
    asm volatile("s_waitcnt vmcnt(0)" ::: "memory");
#pragma unroll
    for (int r = 0; r < 6; ++r) {
      const int hg = h0 - 1 + r;
      half8 v = (half8){0, 0, 0, 0, 0, 0, 0, 0};
      if ((unsigned)hg < (unsigned)HH) {
#pragma unroll
        for (int j = 0; j < 8; ++j) v[j] = (_Float16)fr[r][j];
      }
      *(half8*)(bdst + r * 8192) = v;
    }
  }
#pragma unroll
  for (int kk = 0; kk < 9; ++kk)
#pragma unroll
    for (int nj = 0; nj < 4; ++nj)
      asm volatile("" : "+v"(mv[kk][nj]));         // keep masks resident past drain
  __syncthreads();                                 // B tile visible to all waves

  // per-lane A base: addr(q, o) = (q*1024 + o*8)*2 bytes; q = qb + lg
  const char* abase = (const char*)wt + lg * 2048 + (mw + lr) * 16;

  f32x4 acc[4][4];                                 // [mi][nj], 64 VGPR
#pragma unroll
  for (int mi = 0; mi < 4; ++mi)
#pragma unroll
    for (int nj = 0; nj < 4; ++nj)
      acc[mi][nj] = (f32x4){0.f, 0.f, 0.f, 0.f};

  // ---- barrier-free 9-tap loop ----
#pragma unroll
  for (int kk = 0; kk < 9; ++kk) {
    const int di = (kk * 11) >> 5;               // kk/3
    const int dj = kk - 3 * di;

    // per-nj B geometry + masked fp16 scalar (OOB tap -> m=0, garbage*0)
    const char* Bp[4];
    int xk[4];
    _Float16 mh[4];
#pragma unroll
    for (int nj = 0; nj < 4; ++nj) {
      const int wb = ((nj & 1) << 4) + lr + dj - 1;
      const bool vld = (unsigned)wb < (unsigned)WW;
      const int wc = vld ? wb : 0;
      const int hrow = (nw >> 5) + (nj >> 1) + di;   // 0..5
      Bp[nj] = smem + hrow * 8192 + wc * 256;
      xk[nj] = wc & 15;
      mh[nj] = (_Float16)(vld ? mv[kk][nj] : 0.f);
    }

    __builtin_amdgcn_s_setprio(1);
#pragma unroll
    for (int s = 0; s < 2; ++s) {
      const int qb = kk * 16 + (kh * 2 + s) * 4;   // wave-uniform
      const char* ab = abase + qb * 2048;
      const int q = qb + lg;
      half8 a0 = *(const half8*)(ab);
      half8 a1 = *(const half8*)(ab + 256);
      half8 a2 = *(const half8*)(ab + 512);
      half8 a3 = *(const half8*)(ab + 768);
      half8 b0 = *(const half8*)(Bp[0] + (((q & 15) ^ xk[0]) << 4)) * mh[0];
      half8 b1 = *(const half8*)(Bp[1] + (((q & 15) ^ xk[1]) << 4)) * mh[1];
      half8 b2 = *(const half8*)(Bp[2] + (((q & 15) ^ xk[2]) << 4)) * mh[2];
      half8 b3 = *(const half8*)(Bp[3] + (((q & 15) ^ xk[3]) << 4)) * mh[3];
      acc[0][0] = __builtin_amdgcn_mfma_f32_16x16x32_f16(a0, b0, acc[0][0], 0, 0, 0);
      acc[1][0] = __builtin_amdgcn_mfma_f32_16x16x32_f16(a1, b0, acc[1][0], 0, 0, 0);
      acc[2][0] = __builtin_amdgcn_mfma_f32_16x16x32_f16(a2, b0, acc[2][0], 0, 0, 0);
      acc[3][0] = __builtin_amdgcn_mfma_f32_16x16x32_f16(a3, b0, acc[3][0], 0, 0, 0);
      acc[0][1] = __builtin_amdgcn_mfma_f32_16x16x32_f16(a0, b1, acc[0][1], 0, 0, 0);
      acc[1][1] = __builtin_amdgcn_mfma_f32_16x16x32_f16(a1, b1, acc[1][1], 0, 0, 0);
      acc[2][1] = __builtin_amdgcn_mfma_f32_16x16x32_f16(a2, b1, acc[2][1], 0, 0, 0);
      acc[3][1] = __builtin_amdgcn_mfma_f32_16x16x32_f16(a3, b1, acc[3][1], 0, 0, 0);
      acc[0][2] = __builtin_amdgcn_mfma_f32_16x16x32_f16(a0, b2, acc[0][2], 0, 0, 0);
      acc[1][2] = __builtin_amdgcn_mfma_f32_16x16x32_f16(a1, b2, acc[1][2], 0, 0, 0);
      acc[2][2] = __builtin_amdgcn_mfma_f32_16x16x32_f16(a2, b2, acc[2][2], 0, 0, 0);
      acc[3][2] = __builtin_amdgcn_mfma_f32_16x16x32_f16(a3, b2, acc[3][2], 0, 0, 0);
      acc[0][3] = __builtin_amdgcn_mfma_f32_16x16x32_f16(a0, b3, acc[0][3], 0, 0, 0);
      acc[1][3] = __builtin_amdgcn_mfma_f32_16x16x32_f16(a1, b3, acc[1][3], 0, 0, 0);
      acc[2][3] = __builtin_amdgcn_mfma_f32_16x16x32_f16(a2, b3, acc[2][3], 0, 0, 0);
      acc[3][3] = __builtin_amdgcn_mfma_f32_16x16x32_f16(a3, b3, acc[3][3], 0, 0, 0);
    }
    __builtin_amdgcn_s_setprio(0);
  }

  // ---- K-split reduction through LDS (B region dead after this barrier) ----
  __syncthreads();
  char* red = smem + wq * 17408 + lane * 272;
  if (kh == 1) {
#pragma unroll
    for (int mi = 0; mi < 4; ++mi)
#pragma unroll
      for (int nj = 0; nj < 4; ++nj)
        *(f32x4*)(red + (mi * 4 + nj) * 16) = acc[mi][nj];
  }
  __syncthreads();

  if (kh == 0) {
#pragma unroll
    for (int mi = 0; mi < 4; ++mi)
#pragma unroll
      for (int nj = 0; nj < 4; ++nj) {
        f32x4 p = *(const f32x4*)(red + (mi * 4 + nj) * 16);
        acc[mi][nj].x += p.x; acc[mi][nj].y += p.y;
        acc[mi][nj].z += p.z; acc[mi][nj].w += p.w;
      }

    // ---- epilogue: C/D layout col(l)=lane&15, row(o)=(lane>>4)*4+rr ----
    float* outb = out + (size_t)b * COUT * LTOT + l0;
#pragma unroll
    for (int mi = 0; mi < 4; ++mi) {
#pragma unroll
      for (int rr = 0; rr < 4; ++rr) {
        const int o = mw + mi * 16 + lg * 4 + rr;
        const float bv = bias[o];
        float* orow = outb + (size_t)o * LTOT + nw + lr;
#pragma unroll
        for (int nj = 0; nj < 4; ++nj)
          orow[nj * 16] = acc[mi][nj][rr] + bv;
      }
    }
  }
}

extern "C" void kernel_launch(void* const* d_in, const int* in_sizes, int n_in,
                              void* d_out, int out_size, void* d_ws, size_t ws_size,
                              hipStream_t stream) {
  const float* x    = (const float*)d_in[0];
  const float* mask = (const float*)d_in[1];
  const float* w    = (const float*)d_in[2];
  const float* bias = (const float*)d_in[3];
  float* out = (float*)d_out;
  _Float16* wt = (_Float16*)d_ws;

  (void)hipFuncSetAttribute(reinterpret_cast<const void*>(conv_mfma_kernel),
                            hipFuncAttributeMaxDynamicSharedMemorySize, SMEM_BYTES);

  prep_w_kernel<<<576, 256, 0, stream>>>(w, wt);
  conv_mfma_kernel<<<256, 512, SMEM_BYTES, stream>>>(x, wt, mask, bias, out);
}